// Round 7
// baseline (123.447 us; speedup 1.0000x reference)
//
#include <hip/hip_runtime.h>
#include <hip/hip_bf16.h>
#include <stdint.h>

typedef __attribute__((ext_vector_type(8))) short bf16x8;
typedef __attribute__((ext_vector_type(4))) float f32x4;

#define NB 8192

__device__ __forceinline__ unsigned pkbf(float x, float y) {
    __hip_bfloat162 h = __float22bfloat162_rn(make_float2(x, y));  // v_cvt_pk_bf16_f32 (RNE)
    unsigned r;
    __builtin_memcpy(&r, &h, 4);
    return r;
}

__device__ __forceinline__ uint4 pack8(float4 a, float4 b) {
    uint4 r;
    r.x = pkbf(a.x, a.y);
    r.y = pkbf(a.z, a.w);
    r.z = pkbf(b.x, b.y);
    r.w = pkbf(b.z, b.w);
    return r;
}

// ---------------------------------------------------------------------------
// prep: W[512][2048] fp32 -> bf16, fragment-linear layout for MFMA B-operand.
// Only k < 1024 ever used. Fragment (kb,cb), kb,cb in [0,32):
//   uint4 index = (kb*32 + cb)*64 + lane
//   element j (0..7) = W[cb*16 + (lane&15)][kb*32 + (lane>>4)*8 + j]
// ---------------------------------------------------------------------------
__global__ __launch_bounds__(256)
void prep_w_kernel(const float* __restrict__ W, uint4* __restrict__ Wt) {
    int t = blockIdx.x * 256 + threadIdx.x;   // 0..65535
    int lane = t & 63;
    int frag = t >> 6;                         // kb*32 + cb
    int kb = frag >> 5, cb = frag & 31;
    int o = cb * 16 + (lane & 15);
    int k = kb * 32 + ((lane >> 4) << 3);
    const float* src = W + (size_t)o * 2048 + k;
    float4 a = *(const float4*)src;
    float4 b = *(const float4*)(src + 4);
    Wt[t] = pack8(a, b);
}

// ---------------------------------------------------------------------------
// score kernel v7: 768 blocks x 512 threads (8 waves). node = bid%6,
// tile = bid/6, BM=64, BN=512 (wave w owns cols [w*64,+64)), BK=64.
//
// KEY CHANGE vs v1-v6 (all HBM-latency-bound at ~700 GB/s): the k-loop uses
// RAW s_barrier (no vmcnt drain) + a depth-4 register prefetch ring with
// prefetch distance 3. A-loads stay in flight ACROSS barriers; the compiler
// emits counted vmcnt waits from register deps (never vmcnt(0)).
// __syncthreads (= s_waitcnt vmcnt(0) before s_barrier) was draining the
// HBM pipe once per stage -> ~1 KB in flight per CU vs the ~9 KB Little's
// law needs for 6 TB/s.
//
// Cross-wave safety of raw barrier: LDS data is produced by ds_write from
// registers; 'asm lgkmcnt(0)' before s_barrier makes writes visible. Readers'
// ds_read data lands in registers before their MFMAs issue (compiler lgkmcnt),
// which precedes their barrier arrival -> next stage's overwrite is safe.
// sched_barrier(0) pins issue order: B loads (L2) first, ring loads (HBM)
// last, so waiting on B never drains the ring.
//
// LDS A tile: bf16 fragment-linear, 512 chunks of 16B <-> 512 threads.
// chunk c: frag f=c>>6 (ks=f>>2, mf=f&3), lane l=c&63 holds
//   A[m0 + mf*16 + (l&15)][s*64 + ks*32 + (l>>4)*8 + j], j=0..7.
// Writes and reads lane-linear -> 0 bank conflicts (verified r2/r5/r6).
// ---------------------------------------------------------------------------
__global__ __launch_bounds__(512)
void score_kernel(const float* __restrict__ x0, const float* __restrict__ x1,
                  const float* __restrict__ x2, const float* __restrict__ x3,
                  const float* __restrict__ x4, const float* __restrict__ x5,
                  const float* __restrict__ bias, const float* __restrict__ hvec,
                  const uint4* __restrict__ Wt, float* __restrict__ scores) {
    __shared__ uint4 lA[2][512];      // 2 x 8 KB bf16 tiles
    __shared__ float red[8][64];

    int bid = blockIdx.x;
    int node = bid % 6;
    int tile = bid / 6;               // 0..127
    const float* xp; int dn;
    switch (node) {
        case 0: xp = x0; dn = 1024; break;
        case 1: xp = x1; dn = 512;  break;
        case 2: xp = x2; dn = 512;  break;
        case 3: xp = x3; dn = 512;  break;
        case 4: xp = x4; dn = 1024; break;
        default: xp = x5; dn = 512; break;
    }
    int m0 = tile * 64;
    int t = threadIdx.x;
    int l = t & 63;
    int w = t >> 6;

    int nst = dn >> 6;                // 8 or 16 BK=64 stages

    // staging source: thread t <-> chunk t
    int f = t >> 6;                   // frag id: ks = f>>2, mf = f&3
    int srow = (f & 3) * 16 + (l & 15);
    int scol = (f >> 2) * 32 + ((l >> 4) << 3);
    const float* g1 = xp + (size_t)(m0 + srow) * dn + scol;

    // prefetch ring: depth 4, distance 3. ring[x] = 8 fp32 for one stage.
    float4 ring[4][2];

    // prologue: issue stages 0,1,2 (oldest first)
    ring[0][0] = *(const float4*)(g1);
    ring[0][1] = *(const float4*)(g1 + 4);
    ring[1][0] = *(const float4*)(g1 + 64);
    ring[1][1] = *(const float4*)(g1 + 68);
    ring[2][0] = *(const float4*)(g1 + 128);
    ring[2][1] = *(const float4*)(g1 + 132);
    // cvt stage 0 -> lA[0]  (counted vmcnt: stages 1,2 stay in flight)
    lA[0][t] = pack8(ring[0][0], ring[0][1]);
    asm volatile("s_waitcnt lgkmcnt(0)" ::: "memory");
    __builtin_amdgcn_s_barrier();

    f32x4 acc[4][4];
#pragma unroll
    for (int mf = 0; mf < 4; ++mf)
#pragma unroll
        for (int nf = 0; nf < 4; ++nf)
            acc[mf][nf] = (f32x4){0.f, 0.f, 0.f, 0.f};

    for (int sb = 0; sb < nst; sb += 4) {
#pragma unroll
        for (int j = 0; j < 4; ++j) {
            int s = sb + j;
            int cur = s & 1;
            // (a) B fragments for both kblocks (L2-hot, fragment-linear)
            bf16x8 bfr[2][4];
#pragma unroll
            for (int ks = 0; ks < 2; ++ks) {
                int kb = (s << 1) + ks;
                const uint4* wp = Wt + (((kb << 5) + (w << 2)) << 6) + l;
#pragma unroll
                for (int nf = 0; nf < 4; ++nf) {
                    uint4 u = wp[nf << 6];
                    __builtin_memcpy(&bfr[ks][nf], &u, 16);
                }
            }
            __builtin_amdgcn_sched_barrier(0);
            // (b) ring issue for stage s+3 (newest in the vmem queue)
            if (s + 3 < nst) {
                const float* q = g1 + (size_t)(s + 3) * 64;
                ring[(j + 3) & 3][0] = *(const float4*)q;
                ring[(j + 3) & 3][1] = *(const float4*)(q + 4);
            }
            __builtin_amdgcn_sched_barrier(0);
            // (c) A fragments from LDS + MFMA
#pragma unroll
            for (int ks = 0; ks < 2; ++ks) {
#pragma unroll
                for (int mf = 0; mf < 4; ++mf) {
                    uint4 u = lA[cur][((ks << 2) + mf) * 64 + l];
                    bf16x8 afr;
                    __builtin_memcpy(&afr, &u, 16);
#pragma unroll
                    for (int nf = 0; nf < 4; ++nf)
                        acc[mf][nf] = __builtin_amdgcn_mfma_f32_16x16x32_bf16(
                            afr, bfr[ks][nf], acc[mf][nf], 0, 0, 0);
                }
            }
            // (d) cvt ring slot s+1 -> other LDS buffer (counted vmcnt:
            //     slots s+2, s+3 remain in flight)
            if (s + 1 < nst) {
                lA[cur ^ 1][t] = pack8(ring[(j + 1) & 3][0], ring[(j + 1) & 3][1]);
            }
            // (e) LDS visibility + raw barrier (NO vmcnt drain)
            asm volatile("s_waitcnt lgkmcnt(0)" ::: "memory");
            __builtin_amdgcn_sched_barrier(0);
            __builtin_amdgcn_s_barrier();
        }
    }

    // epilogue: tanh, dot with h, reduce to per-row score
    float bv[4], hv[4];
#pragma unroll
    for (int nf = 0; nf < 4; ++nf) {
        int o = (w << 6) + (nf << 4) + (l & 15);
        bv[nf] = bias[o];
        hv[nf] = hvec[o];
    }
#pragma unroll
    for (int mf = 0; mf < 4; ++mf) {
        float sc[4] = {0.f, 0.f, 0.f, 0.f};
#pragma unroll
        for (int nf = 0; nf < 4; ++nf) {
#pragma unroll
            for (int r = 0; r < 4; ++r) {
                float xv = acc[mf][nf][r] + bv[nf];
                float th = 1.f - 2.f * __builtin_amdgcn_rcpf(1.f + __expf(2.f * xv));
                sc[r] = fmaf(hv[nf], th, sc[r]);
            }
        }
#pragma unroll
        for (int r = 0; r < 4; ++r) {
            float v = sc[r];
            v += __shfl_xor(v, 1);
            v += __shfl_xor(v, 2);
            v += __shfl_xor(v, 4);
            v += __shfl_xor(v, 8);
            if ((l & 15) == 0)
                red[w][(mf << 4) + ((l >> 4) << 2) + r] = v;
        }
    }
    __syncthreads();
    if (t < 64) {
        float ssum = 0.f;
#pragma unroll
        for (int w2 = 0; w2 < 8; ++w2) ssum += red[w2][t];
        scores[node * NB + m0 + t] = ssum;
    }
}

// ---------------------------------------------------------------------------
// z kernel: one wave per batch. softmax over 6 scores, then
// z[0:512]=sum beta_n x_n ; z[512:1024]=b0*ls+b4*ds ; z[1024:2048]=0
// ---------------------------------------------------------------------------
__global__ __launch_bounds__(256)
void z_kernel(const float* __restrict__ x0, const float* __restrict__ x1,
              const float* __restrict__ x2, const float* __restrict__ x3,
              const float* __restrict__ x4, const float* __restrict__ x5,
              const float* __restrict__ scores, float* __restrict__ out) {
    int wv = threadIdx.x >> 6;
    int lane = threadIdx.x & 63;
    int b = (blockIdx.x << 2) + wv;

    float s0 = scores[b];
    float s1 = scores[NB + b];
    float s2 = scores[2 * NB + b];
    float s3 = scores[3 * NB + b];
    float s4 = scores[4 * NB + b];
    float s5 = scores[5 * NB + b];
    float m = fmaxf(fmaxf(fmaxf(s0, s1), fmaxf(s2, s3)), fmaxf(s4, s5));
    float e0 = __expf(s0 - m), e1 = __expf(s1 - m), e2 = __expf(s2 - m);
    float e3 = __expf(s3 - m), e4 = __expf(s4 - m), e5 = __expf(s5 - m);
    float inv = __builtin_amdgcn_rcpf(e0 + e1 + e2 + e3 + e4 + e5);
    float b0 = e0 * inv, b1 = e1 * inv, b2 = e2 * inv;
    float b3 = e3 * inv, b4 = e4 * inv, b5 = e5 * inv;

    const float* pls = x0 + (size_t)b * 1024;
    const float* pA  = x1 + (size_t)b * 512;
    const float* plm = x2 + (size_t)b * 512;
    const float* pAT = x3 + (size_t)b * 512;
    const float* pds = x4 + (size_t)b * 1024;
    const float* pdm = x5 + (size_t)b * 512;
    float* po = out + (size_t)b * 2048;

#pragma unroll
    for (int j = 0; j < 2; ++j) {
        int c = (j << 8) + (lane << 2);
        float4 vls = *(const float4*)(pls + c);
        float4 vA  = *(const float4*)(pA + c);
        float4 vlm = *(const float4*)(plm + c);
        float4 vAT = *(const float4*)(pAT + c);
        float4 vds = *(const float4*)(pds + c);
        float4 vdm = *(const float4*)(pdm + c);
        float4 r;
        r.x = b0*vls.x + b1*vA.x + b2*vlm.x + b3*vAT.x + b4*vds.x + b5*vdm.x;
        r.y = b0*vls.y + b1*vA.y + b2*vlm.y + b3*vAT.y + b4*vds.y + b5*vdm.y;
        r.z = b0*vls.z + b1*vA.z + b2*vlm.z + b3*vAT.z + b4*vds.z + b5*vdm.z;
        r.w = b0*vls.w + b1*vA.w + b2*vlm.w + b3*vAT.w + b4*vds.w + b5*vdm.w;
        *(float4*)(po + c) = r;
    }
#pragma unroll
    for (int j = 0; j < 2; ++j) {
        int c = 512 + (j << 8) + (lane << 2);
        float4 vls = *(const float4*)(pls + c);
        float4 vds = *(const float4*)(pds + c);
        float4 r;
        r.x = b0*vls.x + b4*vds.x;
        r.y = b0*vls.y + b4*vds.y;
        r.z = b0*vls.z + b4*vds.z;
        r.w = b0*vls.w + b4*vds.w;
        *(float4*)(po + c) = r;
    }
    float4 zz = make_float4(0.f, 0.f, 0.f, 0.f);
#pragma unroll
    for (int j = 0; j < 4; ++j) {
        int c = 1024 + (j << 8) + (lane << 2);
        *(float4*)(po + c) = zz;
    }
}

extern "C" void kernel_launch(void* const* d_in, const int* in_sizes, int n_in,
                              void* d_out, int out_size, void* d_ws, size_t ws_size,
                              hipStream_t stream) {
    const float* x0   = (const float*)d_in[0];  // ls  [8192,1024]
    const float* x1   = (const float*)d_in[1];  // A   [8192,512]
    const float* x2   = (const float*)d_in[2];  // lm  [8192,512]
    const float* x3   = (const float*)d_in[3];  // AT  [8192,512]
    const float* x4   = (const float*)d_in[4];  // ds  [8192,1024]
    const float* x5   = (const float*)d_in[5];  // dm  [8192,512]
    const float* W    = (const float*)d_in[6];  // [512,2048]
    const float* bias = (const float*)d_in[7];  // [512]
    const float* hvec = (const float*)d_in[8];  // [512,1]

    uint4* Wt = (uint4*)d_ws;                              // 1 MB
    float* scores = (float*)((char*)d_ws + (1u << 20));    // 6*8192*4 = 192 KB

    prep_w_kernel<<<256, 256, 0, stream>>>(W, Wt);
    score_kernel<<<768, 512, 0, stream>>>(x0, x1, x2, x3, x4, x5, bias, hvec, Wt, scores);
    z_kernel<<<2048, 256, 0, stream>>>(x0, x1, x2, x3, x4, x5, scores, (float*)d_out);
}

// Round 8
// 94.357 us; speedup vs baseline: 1.3083x; 1.3083x over previous
//
#include <hip/hip_runtime.h>
#include <hip/hip_bf16.h>
#include <stdint.h>

typedef __attribute__((ext_vector_type(8))) short bf16x8;
typedef __attribute__((ext_vector_type(4))) float f32x4;

#define NB 8192

__device__ __forceinline__ unsigned pkbf(float x, float y) {
    __hip_bfloat162 h = __float22bfloat162_rn(make_float2(x, y));  // v_cvt_pk_bf16_f32 (RNE)
    unsigned r;
    __builtin_memcpy(&r, &h, 4);
    return r;
}

__device__ __forceinline__ uint4 pack8(float4 a, float4 b) {
    uint4 r;
    r.x = pkbf(a.x, a.y);
    r.y = pkbf(a.z, a.w);
    r.z = pkbf(b.x, b.y);
    r.w = pkbf(b.z, b.w);
    return r;
}

// ---------------------------------------------------------------------------
// prep: W[512][2048] fp32 -> bf16, fragment-linear layout for MFMA B-operand.
// Only k < 1024 ever used. Fragment (kb,cb), kb,cb in [0,32):
//   uint4 index = (kb*32 + cb)*64 + lane
//   element j (0..7) = W[cb*16 + (lane&15)][kb*32 + (lane>>4)*8 + j]
// ---------------------------------------------------------------------------
__global__ __launch_bounds__(256)
void prep_w_kernel(const float* __restrict__ W, uint4* __restrict__ Wt) {
    int t = blockIdx.x * 256 + threadIdx.x;   // 0..65535
    int lane = t & 63;
    int frag = t >> 6;                         // kb*32 + cb
    int kb = frag >> 5, cb = frag & 31;
    int o = cb * 16 + (lane & 15);
    int k = kb * 32 + ((lane >> 4) << 3);
    const float* src = W + (size_t)o * 2048 + k;
    float4 a = *(const float4*)src;
    float4 b = *(const float4*)(src + 4);
    Wt[t] = pack8(a, b);
}

// ---------------------------------------------------------------------------
// score kernel v8: BARRIER-FREE k-loop (the r1-r7 invariant was per-stage
// barrier lockstep: every pipe <15% busy, all structures ~110us, even when
// fully L3-served -> latency serialization, not bandwidth).
// Block stages its WHOLE A panel (BM x DN) to LDS once (fp32->bf16,
// fragment-linear, 128 KB), one __syncthreads, then each of 8 waves runs an
// independent k-loop streaming B from L2 -- waves desync naturally, MFMA of
// one wave covers loads of another (m114 overlap, no barrier to defeat it).
//
// Two shapes, equal per-block work (67 MFLOP, 256 KB A):
//   heavy <4,1024>: BM=64,  nodes {0,4}, wave tile 64x64,  acc[4][4]
//   light <8,512> : BM=128, nodes {1,2,3,5}, wave tile 128x64, acc[8][4]
//     (BM=128 halves light-node B traffic: total B = 256+128 = 384 MB)
// LDS A layout frag-linear: chunk (kb*MFN+mf)*64 + l holds
//   A[m0 + mf*16 + (l&15)][kb*32 + (l>>4)*8 + j], j=0..7  (bf16x8)
// All LDS writes/reads lane-linear -> 0 bank conflicts (verified r2/r5/r6).
// ---------------------------------------------------------------------------
template<int MFN, int DN>
__device__ __forceinline__ void score_body(
        const float* __restrict__ xp, int node, int m0,
        const float* __restrict__ bias, const float* __restrict__ hvec,
        const uint4* __restrict__ Wt, float* __restrict__ scores,
        uint4* lA, float* red) {
    constexpr int BM = MFN * 16;
    constexpr int NKB = DN / 32;      // kblocks of 32
    int t = threadIdx.x;
    int l = t & 63;
    int w = t >> 6;

    // ---- prologue: stage A panel, cvt fp32->bf16, frag-linear ----
#pragma unroll
    for (int j = 0; j < 16; ++j) {
        int f = (t >> 6) + j * 8;     // frag id 0..127
        int kb = f / MFN, mf = f % MFN;
        int row = mf * 16 + (l & 15);
        int k = kb * 32 + ((l >> 4) << 3);
        const float* g = xp + (size_t)(m0 + row) * DN + k;
        float4 a = *(const float4*)g;
        float4 b = *(const float4*)(g + 4);
        lA[f * 64 + l] = pack8(a, b);
    }
    __syncthreads();

    // ---- barrier-free k-loop ----
    f32x4 acc[MFN][4];
#pragma unroll
    for (int mf = 0; mf < MFN; ++mf)
#pragma unroll
        for (int nf = 0; nf < 4; ++nf)
            acc[mf][nf] = (f32x4){0.f, 0.f, 0.f, 0.f};

    // manual depth-1 B prefetch; no barriers -> compiler/HW pipeline freely
    bf16x8 bcur[4];
    {
        const uint4* wp = Wt + ((0 + (w << 2)) << 6) + l;
#pragma unroll
        for (int nf = 0; nf < 4; ++nf) {
            uint4 u = wp[nf << 6];
            __builtin_memcpy(&bcur[nf], &u, 16);
        }
    }
    for (int kb = 0; kb < NKB; ++kb) {
        bf16x8 bnxt[4];
        if (kb + 1 < NKB) {
            const uint4* wp = Wt + ((((kb + 1) << 5) + (w << 2)) << 6) + l;
#pragma unroll
            for (int nf = 0; nf < 4; ++nf) {
                uint4 u = wp[nf << 6];
                __builtin_memcpy(&bnxt[nf], &u, 16);
            }
        }
#pragma unroll
        for (int mf = 0; mf < MFN; ++mf) {
            uint4 u = lA[(kb * MFN + mf) * 64 + l];
            bf16x8 afr;
            __builtin_memcpy(&afr, &u, 16);
#pragma unroll
            for (int nf = 0; nf < 4; ++nf)
                acc[mf][nf] = __builtin_amdgcn_mfma_f32_16x16x32_bf16(
                    afr, bcur[nf], acc[mf][nf], 0, 0, 0);
        }
#pragma unroll
        for (int nf = 0; nf < 4; ++nf) bcur[nf] = bnxt[nf];
    }

    // ---- epilogue: tanh, dot with h, reduce to per-row score ----
    float bv[4], hv[4];
#pragma unroll
    for (int nf = 0; nf < 4; ++nf) {
        int o = (w << 6) + (nf << 4) + (l & 15);
        bv[nf] = bias[o];
        hv[nf] = hvec[o];
    }
#pragma unroll
    for (int mf = 0; mf < MFN; ++mf) {
        float sc[4] = {0.f, 0.f, 0.f, 0.f};
#pragma unroll
        for (int nf = 0; nf < 4; ++nf) {
#pragma unroll
            for (int r = 0; r < 4; ++r) {
                float xv = acc[mf][nf][r] + bv[nf];
                float th = 1.f - 2.f * __builtin_amdgcn_rcpf(1.f + __expf(2.f * xv));
                sc[r] = fmaf(hv[nf], th, sc[r]);
            }
        }
#pragma unroll
        for (int r = 0; r < 4; ++r) {
            float v = sc[r];
            v += __shfl_xor(v, 1);
            v += __shfl_xor(v, 2);
            v += __shfl_xor(v, 4);
            v += __shfl_xor(v, 8);
            if ((l & 15) == 0)
                red[w * BM + (mf << 4) + ((l >> 4) << 2) + r] = v;
        }
    }
    __syncthreads();
    if (t < BM) {
        float ssum = 0.f;
#pragma unroll
        for (int w2 = 0; w2 < 8; ++w2) ssum += red[w2 * BM + t];
        scores[node * NB + m0 + t] = ssum;
    }
}

__global__ __launch_bounds__(512, 2)
void score_kernel(const float* __restrict__ x0, const float* __restrict__ x1,
                  const float* __restrict__ x2, const float* __restrict__ x3,
                  const float* __restrict__ x4, const float* __restrict__ x5,
                  const float* __restrict__ bias, const float* __restrict__ hvec,
                  const uint4* __restrict__ Wt, float* __restrict__ scores) {
    __shared__ uint4 lA[8192];        // 128 KB A panel (both shapes)
    __shared__ float red[8 * 128];    // 4 KB

    int bid = blockIdx.x;
    if (bid < 256) {
        // heavy: nodes 0 (ls) / 4 (ds), DN=1024, BM=64
        const float* xp = (bid & 1) ? x4 : x0;
        int node = (bid & 1) ? 4 : 0;
        int m0 = (bid >> 1) * 64;
        score_body<4, 1024>(xp, node, m0, bias, hvec, Wt, scores, lA, red);
    } else {
        // light: nodes 1,2,3,5, DN=512, BM=128
        int lb = bid - 256;
        int ni = lb & 3;
        const float* xp = (ni == 0) ? x1 : (ni == 1) ? x2 : (ni == 2) ? x3 : x5;
        int node = (ni == 0) ? 1 : (ni == 1) ? 2 : (ni == 2) ? 3 : 5;
        int m0 = (lb >> 2) * 128;
        score_body<8, 512>(xp, node, m0, bias, hvec, Wt, scores, lA, red);
    }
}

// ---------------------------------------------------------------------------
// z kernel: one wave per batch. softmax over 6 scores, then
// z[0:512]=sum beta_n x_n ; z[512:1024]=b0*ls+b4*ds ; z[1024:2048]=0
// ---------------------------------------------------------------------------
__global__ __launch_bounds__(256)
void z_kernel(const float* __restrict__ x0, const float* __restrict__ x1,
              const float* __restrict__ x2, const float* __restrict__ x3,
              const float* __restrict__ x4, const float* __restrict__ x5,
              const float* __restrict__ scores, float* __restrict__ out) {
    int wv = threadIdx.x >> 6;
    int lane = threadIdx.x & 63;
    int b = (blockIdx.x << 2) + wv;

    float s0 = scores[b];
    float s1 = scores[NB + b];
    float s2 = scores[2 * NB + b];
    float s3 = scores[3 * NB + b];
    float s4 = scores[4 * NB + b];
    float s5 = scores[5 * NB + b];
    float m = fmaxf(fmaxf(fmaxf(s0, s1), fmaxf(s2, s3)), fmaxf(s4, s5));
    float e0 = __expf(s0 - m), e1 = __expf(s1 - m), e2 = __expf(s2 - m);
    float e3 = __expf(s3 - m), e4 = __expf(s4 - m), e5 = __expf(s5 - m);
    float inv = __builtin_amdgcn_rcpf(e0 + e1 + e2 + e3 + e4 + e5);
    float b0 = e0 * inv, b1 = e1 * inv, b2 = e2 * inv;
    float b3 = e3 * inv, b4 = e4 * inv, b5 = e5 * inv;

    const float* pls = x0 + (size_t)b * 1024;
    const float* pA  = x1 + (size_t)b * 512;
    const float* plm = x2 + (size_t)b * 512;
    const float* pAT = x3 + (size_t)b * 512;
    const float* pds = x4 + (size_t)b * 1024;
    const float* pdm = x5 + (size_t)b * 512;
    float* po = out + (size_t)b * 2048;

#pragma unroll
    for (int j = 0; j < 2; ++j) {
        int c = (j << 8) + (lane << 2);
        float4 vls = *(const float4*)(pls + c);
        float4 vA  = *(const float4*)(pA + c);
        float4 vlm = *(const float4*)(plm + c);
        float4 vAT = *(const float4*)(pAT + c);
        float4 vds = *(const float4*)(pds + c);
        float4 vdm = *(const float4*)(pdm + c);
        float4 r;
        r.x = b0*vls.x + b1*vA.x + b2*vlm.x + b3*vAT.x + b4*vds.x + b5*vdm.x;
        r.y = b0*vls.y + b1*vA.y + b2*vlm.y + b3*vAT.y + b4*vds.y + b5*vdm.y;
        r.z = b0*vls.z + b1*vA.z + b2*vlm.z + b3*vAT.z + b4*vds.z + b5*vdm.z;
        r.w = b0*vls.w + b1*vA.w + b2*vlm.w + b3*vAT.w + b4*vds.w + b5*vdm.w;
        *(float4*)(po + c) = r;
    }
#pragma unroll
    for (int j = 0; j < 2; ++j) {
        int c = 512 + (j << 8) + (lane << 2);
        float4 vls = *(const float4*)(pls + c);
        float4 vds = *(const float4*)(pds + c);
        float4 r;
        r.x = b0*vls.x + b4*vds.x;
        r.y = b0*vls.y + b4*vds.y;
        r.z = b0*vls.z + b4*vds.z;
        r.w = b0*vls.w + b4*vds.w;
        *(float4*)(po + c) = r;
    }
    float4 zz = make_float4(0.f, 0.f, 0.f, 0.f);
#pragma unroll
    for (int j = 0; j < 4; ++j) {
        int c = 1024 + (j << 8) + (lane << 2);
        *(float4*)(po + c) = zz;
    }
}

extern "C" void kernel_launch(void* const* d_in, const int* in_sizes, int n_in,
                              void* d_out, int out_size, void* d_ws, size_t ws_size,
                              hipStream_t stream) {
    const float* x0   = (const float*)d_in[0];  // ls  [8192,1024]
    const float* x1   = (const float*)d_in[1];  // A   [8192,512]
    const float* x2   = (const float*)d_in[2];  // lm  [8192,512]
    const float* x3   = (const float*)d_in[3];  // AT  [8192,512]
    const float* x4   = (const float*)d_in[4];  // ds  [8192,1024]
    const float* x5   = (const float*)d_in[5];  // dm  [8192,512]
    const float* W    = (const float*)d_in[6];  // [512,2048]
    const float* bias = (const float*)d_in[7];  // [512]
    const float* hvec = (const float*)d_in[8];  // [512,1]

    uint4* Wt = (uint4*)d_ws;                              // 1 MB
    float* scores = (float*)((char*)d_ws + (1u << 20));    // 6*8192*4 = 192 KB

    prep_w_kernel<<<256, 256, 0, stream>>>(W, Wt);
    score_kernel<<<512, 512, 0, stream>>>(x0, x1, x2, x3, x4, x5, bias, hvec, Wt, scores);
    z_kernel<<<2048, 256, 0, stream>>>(x0, x1, x2, x3, x4, x5, scores, (float*)d_out);
}